// Round 4
// baseline (300.260 us; speedup 1.0000x reference)
//
#include <hip/hip_runtime.h>

// MeanShift++ dense-grid, distinct-bin formulation, v16.
// = v12 (246us, best) with ONE change in the conv phase: DYNAMIC CHUNK
// WORK-STEALING. v12 statically partitioned NC~2500 chunks over 1792 conv
// blocks (1.4-1.6 chunks/block -> 2:1 runtime imbalance; k_fused measured
// OccupancyPercent ~42%, VALUBusy ~2.5% => latency-bound kernel spends its
// second half at <50% residency). Now each block grabs chunks from a global
// atomic queue (one atomicAdd per chunk) -> +/-1 balance at any K.
// k_fin stays folded into k_map (v13 part, mechanically sound).
// Dead levers (measured): 4-wave finalize + mask pre-test (v15, +14us),
// separable z-pass conv (v14, +36us: conv is NOT tap-bound), unsorted
// direct-append list (v13, +44us: sorted compactM list is load-bearing),
// region-LDS-tile conv (r11, -52%), flattened-tap 8-lane conv (r8, -78%),
// XCD chunk partition (r12, neutral; superseded by stealing).

constexpr float BW   = 0.1f;
constexpr float TOL2 = 1e-6f;            // (1e-3)^2
constexpr int DIM  = 112, OFF = 56;      // bins in [-56,55]; |x|<5.6 covered
constexpr int DIM2 = DIM * DIM;
constexpr int CELLS = DIM * DIM * DIM;   // 1,404,928
constexpr int CLW = CELLS / 32;          // 43,904 mask words
constexpr int RDIM = 16, RC = 7;         // 16^3 regions of 7^3 cells
constexpr int NREG = RDIM * RDIM * RDIM; // 4096
constexpr int RC3 = RC * RC * RC;        // 343
constexpr int NB_A = 128, BLK = 256;
constexpr int NF = 2048;                 // k_fused grid
constexpr int IPB = 51;                  // conv items per block (51*5=255 thr)
constexpr float FPS = 16777216.0f;       // 2^24 fixed-point scale
constexpr double FPSI = 1.0 / 16777216.0;

typedef float vf2 __attribute__((ext_vector_type(2)));

__device__ __forceinline__ int clampb(int v) { return v < 0 ? 0 : (v > DIM - 1 ? DIM - 1 : v); }
__device__ __forceinline__ int binf(float v) { return clampb((int)(v / BW) + OFF); }  // IEEE div+trunc == ref
__device__ __forceinline__ int flatb(int bx, int by, int bz) { return (bx * DIM + by) * DIM + bz; }
__device__ __forceinline__ int regOf(int bx, int by, int bz) {
    return ((bx / RC) * RDIM + (by / RC)) * RDIM + (bz / RC);
}
__device__ __forceinline__ int lcOf(int bx, int by, int bz) {
    return ((bx % RC) * RC + (by % RC)) * RC + (bz % RC);
}

__device__ __forceinline__ void pk_add(float* p, float a, float b) {
#if defined(__has_builtin) && __has_builtin(__builtin_amdgcn_global_atomic_fadd_v2f32)
    vf2 v = {a, b};
    __builtin_amdgcn_global_atomic_fadd_v2f32((vf2*)p, v);
#else
    atomicAdd(p, a);
    atomicAdd(p + 1, b);
#endif
}

// ---- pass A1: per-block region histogram (LDS) + streaming zero of grids A,B ----
__launch_bounds__(BLK)
__global__ void k_histA(const float* __restrict__ X, int n, int* __restrict__ blockHist,
                        float4* __restrict__ zeroA, float4* __restrict__ zeroB) {
    __shared__ int h[NREG];
    for (int i = threadIdx.x; i < NREG; i += blockDim.x) h[i] = 0;
    __syncthreads();
    int stride = gridDim.x * blockDim.x;
    for (int i = blockIdx.x * blockDim.x + threadIdx.x; i < n; i += stride) {
        float x = X[3 * i + 0], y = X[3 * i + 1], z = X[3 * i + 2];
        atomicAdd(&h[regOf(binf(x), binf(y), binf(z))], 1);
    }
    __syncthreads();
    for (int i = threadIdx.x; i < NREG; i += blockDim.x)
        blockHist[blockIdx.x * NREG + i] = h[i];
    for (int i = blockIdx.x * blockDim.x + threadIdx.x; i < CELLS; i += stride) {
        zeroA[i] = make_float4(0.f, 0.f, 0.f, 0.f);
        zeroB[i] = make_float4(0.f, 0.f, 0.f, 0.f);
    }
}

// ---- pass A2: per-region column scan over blocks ----
__global__ void k_colscan(int* __restrict__ blockHist, int* __restrict__ regionPS) {
    int r = blockIdx.x * blockDim.x + threadIdx.x;
    if (r >= NREG) return;
    int run = 0;
    for (int b = 0; b < NB_A; ++b) {
        int idx = b * NREG + r;
        int v = blockHist[idx];
        blockHist[idx] = run;
        run += v;
    }
    regionPS[r] = run;
}

// ---- pass A3: exclusive prefix over 4096 region totals ----
__launch_bounds__(1024)
__global__ void k_regprefix(int* __restrict__ regionPS) {
    __shared__ int buf[1024];
    int t = threadIdx.x;
    int v0 = regionPS[4 * t + 0], v1 = regionPS[4 * t + 1];
    int v2 = regionPS[4 * t + 2], v3 = regionPS[4 * t + 3];
    int s = v0 + v1 + v2 + v3;
    buf[t] = s;
    __syncthreads();
    for (int d = 1; d < 1024; d <<= 1) {
        int add = (t >= d) ? buf[t - d] : 0;
        __syncthreads();
        buf[t] += add;
        __syncthreads();
    }
    int excl = buf[t] - s;
    regionPS[4 * t + 0] = excl;
    regionPS[4 * t + 1] = excl + v0;
    regionPS[4 * t + 2] = excl + v0 + v1;
    regionPS[4 * t + 3] = excl + v0 + v1 + v2;
    if (t == 1023) regionPS[4096] = buf[1023];
}

// ---- pass A4: scatter points into region buckets + streaming zero of grid C ----
__launch_bounds__(BLK)
__global__ void k_scatterA(const float* __restrict__ X, int n,
                           const int* __restrict__ blockHist,
                           const int* __restrict__ regionPS,
                           float4* __restrict__ bucket, float4* __restrict__ zeroC) {
    __shared__ int cur[NREG];
    for (int i = threadIdx.x; i < NREG; i += blockDim.x) cur[i] = 0;
    __syncthreads();
    int stride = gridDim.x * blockDim.x;
    for (int i = blockIdx.x * blockDim.x + threadIdx.x; i < n; i += stride) {
        float x = X[3 * i + 0], y = X[3 * i + 1], z = X[3 * i + 2];
        int r = regOf(binf(x), binf(y), binf(z));
        int pos = regionPS[r] + blockHist[blockIdx.x * NREG + r] + atomicAdd(&cur[r], 1);
        bucket[pos] = make_float4(x, y, z, __int_as_float(i));
    }
    for (int i = blockIdx.x * blockDim.x + threadIdx.x; i < CELLS; i += stride)
        zeroC[i] = make_float4(0.f, 0.f, 0.f, 0.f);
}

// ---- pass B: one block/region — LDS int-atomic accumulate, compact, PIdx ----
__launch_bounds__(BLK)
__global__ void k_binB(const float4* __restrict__ bucket, const int* __restrict__ regionPS,
                       float4* __restrict__ A, int* __restrict__ E0,
                       int* __restrict__ PIdx, int* __restrict__ gM0) {
    __shared__ unsigned long long aX[RC3], aY[RC3], aZ[RC3];
    __shared__ unsigned aC[RC3];
    __shared__ int cidx[RC3];
    __shared__ int cnt, cur, sBase;
    int r = blockIdx.x;
    for (int c = threadIdx.x; c < RC3; c += blockDim.x) {
        aX[c] = 0ull; aY[c] = 0ull; aZ[c] = 0ull; aC[c] = 0u;
    }
    if (threadIdx.x == 0) { cnt = 0; cur = 0; }
    __syncthreads();
    int start = regionPS[r], end = regionPS[r + 1];
    for (int i = start + threadIdx.x; i < end; i += blockDim.x) {
        float4 p = bucket[i];
        int lc = lcOf(binf(p.x), binf(p.y), binf(p.z));
        atomicAdd(&aX[lc], (unsigned long long)(long long)rintf(p.x * FPS));
        atomicAdd(&aY[lc], (unsigned long long)(long long)rintf(p.y * FPS));
        atomicAdd(&aZ[lc], (unsigned long long)(long long)rintf(p.z * FPS));
        atomicAdd(&aC[lc], 1u);
    }
    __syncthreads();
    int myc = 0;
    for (int c = threadIdx.x; c < RC3; c += blockDim.x)
        if (aC[c] > 0u) ++myc;
    if (myc) atomicAdd(&cnt, myc);
    __syncthreads();
    if (threadIdx.x == 0 && cnt > 0) sBase = atomicAdd(gM0, cnt);
    __syncthreads();
    int rx = r / (RDIM * RDIM), ry = (r / RDIM) % RDIM, rz = r % RDIM;
    for (int c = threadIdx.x; c < RC3; c += blockDim.x) {
        if (aC[c] > 0u) {
            int idx = sBase + atomicAdd(&cur, 1);
            cidx[c] = idx;
            int bx = rx * RC + c / (RC * RC);
            int by = ry * RC + (c / RC) % RC;
            int bz = rz * RC + c % RC;
            int b = flatb(bx, by, bz);
            E0[idx] = b;
            A[b] = make_float4((float)((double)(long long)aX[c] * FPSI),
                               (float)((double)(long long)aY[c] * FPSI),
                               (float)((double)(long long)aZ[c] * FPSI),
                               (float)aC[c]);
        }
    }
    __syncthreads();
    for (int i = start + threadIdx.x; i < end; i += blockDim.x) {
        float4 p = bucket[i];
        int lc = lcOf(binf(p.x), binf(p.y), binf(p.z));
        PIdx[__float_as_int(p.w)] = cidx[lc];
    }
}

// ---- fused per-step kernel ----
// Blocks [0, BC): conv, 51 items/chunk, 5 threads/item (one dx-plane each),
//   row-contiguous taps, LDS reduce; finalize by wave 0 with head-flag
//   segmented dedup (adjacent equal targets merge; leaders issue atomics).
//   Chunks are pulled from a global atomic queue (qCtr) for +/-1 balance.
// Blocks [BC, NF): grid-stride misc (upd / targeted clear).
__launch_bounds__(BLK)
__global__ void k_fused(
    const float4* __restrict__ src, const int* __restrict__ list, const int* __restrict__ pK,
    int* __restrict__ qCtr,
    float4* __restrict__ REo, int* __restrict__ IDXo, float4* __restrict__ eposInit,
    float4* __restrict__ tgt, unsigned* __restrict__ clT,
    int updS, const float* __restrict__ X, int n, const int* __restrict__ PIdx,
    const float4* __restrict__ REp, const int* __restrict__ IDXp,
    const int* __restrict__ pM0, float4* __restrict__ epos,
    unsigned* __restrict__ notConv,
    const int* __restrict__ clearList, const int* __restrict__ pKc,
    float4* __restrict__ clearGrid, int lastStep) {
    __shared__ float4 sh[BLK];
    __shared__ unsigned sFlag;
    __shared__ int sChunk;
    if (threadIdx.x == 0) sFlag = 0;
    __syncthreads();
    int K = *pK;
    int NC = (K + IPB - 1) / IPB;        // total conv chunks
    int BC = NC;
    if (BC > NF - 256) BC = NF - 256;    // always keep misc blocks
    const float t5[5] = {1.f, 2.f, 3.f, 2.f, 1.f};
    bool moved = false;

    if ((int)blockIdx.x < BC) {
        // ---------------- conv blocks: work-steal chunks ----------------
        for (;;) {
            if (threadIdx.x == 0) sChunk = atomicAdd(qCtr, 1);
            __syncthreads();
            int ib = sChunk;
            if (ib >= NC) break;
            int li = threadIdx.x / 5;
            int dx = threadIdx.x % 5;
            int item = ib * IPB + li;
            float4 part = make_float4(0.f, 0.f, 0.f, 0.f);
            if (li < IPB && item < K) {
                int b = list[item];
                int bx = b / DIM2, rem = b % DIM2;
                int by = rem / DIM, bz = rem % DIM;
                int ix = bx + dx - 2;
                if ((unsigned)ix < (unsigned)DIM) {
                    float wx = t5[dx];
                    if (by >= 2 && by <= DIM - 3 && bz >= 2 && bz <= DIM - 3) {
                        #pragma unroll
                        for (int dy = 0; dy < 5; ++dy) {
                            float wxy = wx * t5[dy];
                            const float4* row = src + flatb(ix, by + dy - 2, bz - 2);
                            #pragma unroll
                            for (int dz = 0; dz < 5; ++dz) {
                                float w = wxy * t5[dz];
                                float4 e = row[dz];
                                part.x = fmaf(w, e.x, part.x);
                                part.y = fmaf(w, e.y, part.y);
                                part.z = fmaf(w, e.z, part.z);
                                part.w = fmaf(w, e.w, part.w);
                            }
                        }
                    } else {
                        for (int dy = 0; dy < 5; ++dy) {
                            int iy = by + dy - 2;
                            if ((unsigned)iy >= (unsigned)DIM) continue;
                            float wxy = wx * t5[dy];
                            for (int dz = 0; dz < 5; ++dz) {
                                int iz = bz + dz - 2;
                                if ((unsigned)iz >= (unsigned)DIM) continue;
                                float w = wxy * t5[dz];
                                float4 e = src[flatb(ix, iy, iz)];
                                part.x = fmaf(w, e.x, part.x);
                                part.y = fmaf(w, e.y, part.y);
                                part.z = fmaf(w, e.z, part.z);
                                part.w = fmaf(w, e.w, part.w);
                            }
                        }
                    }
                }
            }
            sh[threadIdx.x] = part;
            __syncthreads();
            if (threadIdx.x < 64) {
                // finalize by wave 0; head-flag segmented dedup on target bin
                int item2 = ib * IPB + threadIdx.x;
                bool valid = (threadIdx.x < IPB) && (item2 < K);
                int bn = -1;
                float4 sv = make_float4(0.f, 0.f, 0.f, 0.f);
                if (valid) {
                    int base5 = threadIdx.x * 5;
                    float4 a0 = sh[base5 + 0], a1 = sh[base5 + 1], a2 = sh[base5 + 2];
                    float4 a3 = sh[base5 + 3], a4 = sh[base5 + 4];
                    float sx = a0.x + a1.x + a2.x + a3.x + a4.x;
                    float sy = a0.y + a1.y + a2.y + a3.y + a4.y;
                    float sz = a0.z + a1.z + a2.z + a3.z + a4.z;
                    float sc = a0.w + a1.w + a2.w + a3.w + a4.w;
                    int b = list[item2];
                    float W = src[b].w;     // center count (occupied => sc>0)
                    float4 np = make_float4(sx / sc, sy / sc, sz / sc, W);
                    REo[item2] = np;
                    IDXo[b] = item2;
                    if (eposInit) eposInit[item2] = np;
                    if (!lastStep) {
                        bn = flatb(binf(np.x), binf(np.y), binf(np.z));
                        sv = make_float4(W * np.x, W * np.y, W * np.z, W);
                    }
                }
                if (!lastStep) {
                    // run heads: first lane or key differs from previous lane
                    int pbn = __shfl_up(bn, 1, 64);
                    unsigned f = (threadIdx.x == 0 || pbn != bn) ? 1u : 0u;
                    // leader = run end (next lane is a head, or last lane)
                    unsigned nf = __shfl_down(f, 1, 64);
                    bool leader = valid && (threadIdx.x == 63 || nf != 0u);
                    // flagged Hillis-Steele segmented inclusive sum
                    #pragma unroll
                    for (int off = 1; off < 64; off <<= 1) {
                        float ox = __shfl_up(sv.x, off, 64);
                        float oy = __shfl_up(sv.y, off, 64);
                        float oz = __shfl_up(sv.z, off, 64);
                        float ow = __shfl_up(sv.w, off, 64);
                        unsigned of = __shfl_up(f, off, 64);
                        if ((int)threadIdx.x >= off) {
                            if (!f) { sv.x += ox; sv.y += oy; sv.z += oz; sv.w += ow; }
                            f |= of;
                        }
                    }
                    if (leader) {
                        float* cell = (float*)&tgt[bn];
                        pk_add(cell + 0, sv.x, sv.y);
                        pk_add(cell + 2, sv.z, sv.w);
                        atomicOr(&clT[(unsigned)bn >> 5], 1u << (bn & 31));
                    }
                }
            }
            __syncthreads();    // sh + sChunk reuse
        }
    } else {
        // ---------------- misc blocks ----------------
        int U = (updS > 0) ? (X ? n : *pM0) : 0;
        int CL = clearList ? *pKc : 0;
        int total = U + CL;
        bool done = false;
        if (updS > 1) {
            for (int t = 1; t < updS; ++t) done |= (notConv[t] == 0u);
        }
        int stride = (NF - BC) * blockDim.x;
        for (int idx = (blockIdx.x - BC) * blockDim.x + threadIdx.x; idx < total;
             idx += stride) {
            if (idx < U) {
                int e = idx;
                if (X) {  // per-point step-1 convergence via PIdx
                    float x = X[3 * e + 0], y = X[3 * e + 1], z = X[3 * e + 2];
                    float4 rr = REp[PIdx[e]];
                    float ex = rr.x - x, ey = rr.y - y, ez = rr.z - z;
                    moved |= (fmaf(ex, ex, fmaf(ey, ey, ez * ez)) > TOL2);
                } else if (!done) {  // per-entry update to step-updS position
                    float4 p = epos[e];
                    int j = IDXp[flatb(binf(p.x), binf(p.y), binf(p.z))];
                    float4 rr = REp[j];
                    float ex = rr.x - p.x, ey = rr.y - p.y, ez = rr.z - p.z;
                    moved |= (fmaf(ex, ex, fmaf(ey, ey, ez * ez)) > TOL2);
                    epos[e] = make_float4(rr.x, rr.y, rr.z, p.w);
                }
            } else {
                clearGrid[clearList[idx - U]] = make_float4(0.f, 0.f, 0.f, 0.f);
            }
        }
    }
    if (moved) sFlag = 1;
    __syncthreads();
    if (threadIdx.x == 0 && updS > 0 && sFlag) notConv[updS] = 1u;
}

// ---- mask -> bin-sorted list (block scan, 1 atomic/block), clears mask ----
__launch_bounds__(BLK)
__global__ void k_compactM(unsigned* __restrict__ mask, int* __restrict__ listOut,
                           int* __restrict__ pKout) {
    __shared__ int scan[BLK];
    __shared__ int sBase;
    int i = blockIdx.x * blockDim.x + threadIdx.x;
    unsigned w = (i < CLW) ? mask[i] : 0u;
    if (i < CLW && w) mask[i] = 0u;
    int c = __popc(w);
    scan[threadIdx.x] = c;
    __syncthreads();
    for (int d = 1; d < BLK; d <<= 1) {
        int add = (threadIdx.x >= (unsigned)d) ? scan[threadIdx.x - d] : 0;
        __syncthreads();
        scan[threadIdx.x] += add;
        __syncthreads();
    }
    if (threadIdx.x == BLK - 1) {
        int tot = scan[BLK - 1];
        sBase = tot ? atomicAdd(pKout, tot) : 0;
    }
    __syncthreads();
    int base = sBase + scan[threadIdx.x] - c;
    int bb = i * 32;
    while (w) {
        int b = __ffs(w) - 1;
        listOut[base++] = bb + b;
        w &= w - 1;
    }
}

// ---- per-point output: gather epos via PIdx, optional last hop via REa/IDXa ----
__global__ void k_map(const int* __restrict__ PIdx, int n, const float4* __restrict__ epos,
                      const float4* __restrict__ REa, const int* __restrict__ IDXa,
                      const unsigned* __restrict__ notConv, float* __restrict__ out) {
    bool done = false;
    for (int t = 1; t <= 4; ++t) done |= (notConv[t] == 0u);
    int i = blockIdx.x * blockDim.x + threadIdx.x;
    if (i >= n) return;
    float4 p = epos[PIdx[i]];
    if (!done) {
        float4 rr = REa[IDXa[flatb(binf(p.x), binf(p.y), binf(p.z))]];
        p.x = rr.x; p.y = rr.y; p.z = rr.z;
    }
    out[3 * i + 0] = p.x;
    out[3 * i + 1] = p.y;
    out[3 * i + 2] = p.z;
}

extern "C" void kernel_launch(void* const* d_in, const int* in_sizes, int n_in,
                              void* d_out, int out_size, void* d_ws, size_t ws_size,
                              hipStream_t stream) {
    const float* X = (const float*)d_in[0];
    int n = in_sizes[0] / 3;

    char* ws = (char*)d_ws;
    int*      cnt     = (int*)ws;        // cnt[1..5] list sizes
    unsigned* notConv = (unsigned*)(ws + 32);
    int*      qc      = (int*)(ws + 64); // qc[0..4] chunk queues (zeroed by memset)
    size_t mB = (size_t)CLW * 4;
    size_t gB = (size_t)CELLS * 16;
    unsigned* m0 = (unsigned*)(ws + 256);
    unsigned* m1 = (unsigned*)(ws + 256 + mB);
    float4* A = (float4*)(ws + 256 + 2 * mB);
    float4* B = (float4*)((char*)A + gB);
    float4* C = (float4*)((char*)B + gB);
    int* IDXa = (int*)((char*)C + gB);
    int* IDXb = IDXa + CELLS;
    float4* REa  = (float4*)(IDXb + CELLS);
    float4* REb  = REa + n;
    float4* epos = REb + n;
    int* E0   = (int*)(epos + n);
    int* La   = E0 + n;
    int* Lb   = La + n;
    int* Lc   = Lb + n;
    int* Ld   = Lc + n;
    int* PIdx = Ld + n;
    float4* bucket = (float4*)(PIdx + n);
    int* blockHist = (int*)(bucket + n);
    int* regionPS  = blockHist + NB_A * NREG;

    // meta + masks only (A,B zeroed in histA, C in scatterA)
    hipMemsetAsync(ws, 0, 256 + 2 * mB, stream);

    const int NCM = (CLW + BLK - 1) / BLK;   // compactM blocks

    k_histA<<<NB_A, BLK, 0, stream>>>(X, n, blockHist, A, B);
    k_colscan<<<NREG / BLK, BLK, 0, stream>>>(blockHist, regionPS);
    k_regprefix<<<1, 1024, 0, stream>>>(regionPS);
    k_scatterA<<<NB_A, BLK, 0, stream>>>(X, n, blockHist, regionPS, bucket, C);
    k_binB<<<NREG, BLK, 0, stream>>>(bucket, regionPS, A, E0, PIdx, &cnt[1]);

    // F1: conv A/E0 -> REa/IDXa (+epos init); scatter->B claim m0
    k_fused<<<NF, BLK, 0, stream>>>(A, E0, &cnt[1], &qc[0], REa, IDXa, epos,
                                    B, m0,
                                    0, nullptr, n, nullptr, nullptr, nullptr, nullptr,
                                    nullptr, notConv, nullptr, nullptr, nullptr, 0);
    k_compactM<<<NCM, BLK, 0, stream>>>(m0, La, &cnt[2]);
    // F2: conv B/La -> REb/IDXb; scatter->C claim m1; upd1 via PIdx (REa); clear A via E0
    k_fused<<<NF, BLK, 0, stream>>>(B, La, &cnt[2], &qc[1], REb, IDXb, nullptr,
                                    C, m1,
                                    1, X, n, PIdx, REa, IDXa, &cnt[1], nullptr,
                                    notConv, E0, &cnt[1], A, 0);
    k_compactM<<<NCM, BLK, 0, stream>>>(m1, Lb, &cnt[3]);
    // F3: conv C/Lb -> REa/IDXa; scatter->A claim m0; upd2 (REb/IDXb); clear B via La
    k_fused<<<NF, BLK, 0, stream>>>(C, Lb, &cnt[3], &qc[2], REa, IDXa, nullptr,
                                    A, m0,
                                    2, nullptr, n, nullptr, REb, IDXb, &cnt[1], epos,
                                    notConv, La, &cnt[2], B, 0);
    k_compactM<<<NCM, BLK, 0, stream>>>(m0, Lc, &cnt[4]);
    // F4: conv A/Lc -> REb/IDXb; scatter->B claim m1; upd3 (REa/IDXa)
    k_fused<<<NF, BLK, 0, stream>>>(A, Lc, &cnt[4], &qc[3], REb, IDXb, nullptr,
                                    B, m1,
                                    3, nullptr, n, nullptr, REa, IDXa, &cnt[1], epos,
                                    notConv, nullptr, nullptr, nullptr, 0);
    k_compactM<<<NCM, BLK, 0, stream>>>(m1, Ld, &cnt[5]);
    // F5: conv B/Ld -> REa/IDXa (conv only); upd4 (REb/IDXb)
    k_fused<<<NF, BLK, 0, stream>>>(B, Ld, &cnt[5], &qc[4], REa, IDXa, nullptr,
                                    nullptr, nullptr,
                                    4, nullptr, n, nullptr, REb, IDXb, &cnt[1], epos,
                                    notConv, nullptr, nullptr, nullptr, 1);

    k_map<<<(n + BLK - 1) / BLK, BLK, 0, stream>>>(PIdx, n, epos, REa, IDXa,
                                                   notConv, (float*)d_out);
}

// Round 5
// 281.098 us; speedup vs baseline: 1.0682x; 1.0682x over previous
//
#include <hip/hip_runtime.h>

// MeanShift++ dense-grid, distinct-bin formulation, v17.
// = v12 (246us, best) + MASK/ATOMICOR ELIMINATION: finalize leaders no longer
// atomicOr a 512-bins-per-line occupancy mask (suspected same-line atomic
// serialization = the latency floor: VALU 3%, HBM 7%, occ 42%, and only
// finalize-path edits ever moved duration). Next-step lists are now built by
// k_compactG: stream the scatter-target grid's .w channel (w>0 iff bin
// received weight; sums of positive counts) and compact cell indices --
// perfectly sorted, coalesced 22.5MB read, ~4us. Masks, mask memset, mask
// clears: deleted. pk_add scatter unchanged.
// Dead levers (measured): chunk work-steal queue (v16, +54us: same-line queue
// atomics serialize block startup; NC<conv blocks so balance was never the
// issue), 4-wave finalize + mask pre-test (v15, +14us), separable z-pass conv
// (v14, +36us: conv is NOT tap-bound), unsorted direct-append list (v13,
// +44us: sorted list is load-bearing), region-LDS-tile conv (r11, -52%),
// flattened-tap 8-lane conv (r8, -78%), XCD chunk partition (r12, neutral).

constexpr float BW   = 0.1f;
constexpr float TOL2 = 1e-6f;            // (1e-3)^2
constexpr int DIM  = 112, OFF = 56;      // bins in [-56,55]; |x|<5.6 covered
constexpr int DIM2 = DIM * DIM;
constexpr int CELLS = DIM * DIM * DIM;   // 1,404,928
constexpr int RDIM = 16, RC = 7;         // 16^3 regions of 7^3 cells
constexpr int NREG = RDIM * RDIM * RDIM; // 4096
constexpr int RC3 = RC * RC * RC;        // 343
constexpr int NB_A = 128, BLK = 256;
constexpr int NF = 2048;                 // k_fused grid
constexpr int IPB = 51;                  // conv items per block (51*5=255 thr)
constexpr int CPT = 32;                  // compactG cells per thread
constexpr int NBG = (CELLS + BLK * CPT - 1) / (BLK * CPT);  // 172 blocks
constexpr float FPS = 16777216.0f;       // 2^24 fixed-point scale
constexpr double FPSI = 1.0 / 16777216.0;

typedef float vf2 __attribute__((ext_vector_type(2)));

__device__ __forceinline__ int clampb(int v) { return v < 0 ? 0 : (v > DIM - 1 ? DIM - 1 : v); }
__device__ __forceinline__ int binf(float v) { return clampb((int)(v / BW) + OFF); }  // IEEE div+trunc == ref
__device__ __forceinline__ int flatb(int bx, int by, int bz) { return (bx * DIM + by) * DIM + bz; }
__device__ __forceinline__ int regOf(int bx, int by, int bz) {
    return ((bx / RC) * RDIM + (by / RC)) * RDIM + (bz / RC);
}
__device__ __forceinline__ int lcOf(int bx, int by, int bz) {
    return ((bx % RC) * RC + (by % RC)) * RC + (bz % RC);
}

__device__ __forceinline__ void pk_add(float* p, float a, float b) {
#if defined(__has_builtin) && __has_builtin(__builtin_amdgcn_global_atomic_fadd_v2f32)
    vf2 v = {a, b};
    __builtin_amdgcn_global_atomic_fadd_v2f32((vf2*)p, v);
#else
    atomicAdd(p, a);
    atomicAdd(p + 1, b);
#endif
}

// ---- pass A1: per-block region histogram (LDS) + streaming zero of grids A,B ----
__launch_bounds__(BLK)
__global__ void k_histA(const float* __restrict__ X, int n, int* __restrict__ blockHist,
                        float4* __restrict__ zeroA, float4* __restrict__ zeroB) {
    __shared__ int h[NREG];
    for (int i = threadIdx.x; i < NREG; i += blockDim.x) h[i] = 0;
    __syncthreads();
    int stride = gridDim.x * blockDim.x;
    for (int i = blockIdx.x * blockDim.x + threadIdx.x; i < n; i += stride) {
        float x = X[3 * i + 0], y = X[3 * i + 1], z = X[3 * i + 2];
        atomicAdd(&h[regOf(binf(x), binf(y), binf(z))], 1);
    }
    __syncthreads();
    for (int i = threadIdx.x; i < NREG; i += blockDim.x)
        blockHist[blockIdx.x * NREG + i] = h[i];
    for (int i = blockIdx.x * blockDim.x + threadIdx.x; i < CELLS; i += stride) {
        zeroA[i] = make_float4(0.f, 0.f, 0.f, 0.f);
        zeroB[i] = make_float4(0.f, 0.f, 0.f, 0.f);
    }
}

// ---- pass A2: per-region column scan over blocks ----
__global__ void k_colscan(int* __restrict__ blockHist, int* __restrict__ regionPS) {
    int r = blockIdx.x * blockDim.x + threadIdx.x;
    if (r >= NREG) return;
    int run = 0;
    for (int b = 0; b < NB_A; ++b) {
        int idx = b * NREG + r;
        int v = blockHist[idx];
        blockHist[idx] = run;
        run += v;
    }
    regionPS[r] = run;
}

// ---- pass A3: exclusive prefix over 4096 region totals ----
__launch_bounds__(1024)
__global__ void k_regprefix(int* __restrict__ regionPS) {
    __shared__ int buf[1024];
    int t = threadIdx.x;
    int v0 = regionPS[4 * t + 0], v1 = regionPS[4 * t + 1];
    int v2 = regionPS[4 * t + 2], v3 = regionPS[4 * t + 3];
    int s = v0 + v1 + v2 + v3;
    buf[t] = s;
    __syncthreads();
    for (int d = 1; d < 1024; d <<= 1) {
        int add = (t >= d) ? buf[t - d] : 0;
        __syncthreads();
        buf[t] += add;
        __syncthreads();
    }
    int excl = buf[t] - s;
    regionPS[4 * t + 0] = excl;
    regionPS[4 * t + 1] = excl + v0;
    regionPS[4 * t + 2] = excl + v0 + v1;
    regionPS[4 * t + 3] = excl + v0 + v1 + v2;
    if (t == 1023) regionPS[4096] = buf[1023];
}

// ---- pass A4: scatter points into region buckets + streaming zero of grid C ----
__launch_bounds__(BLK)
__global__ void k_scatterA(const float* __restrict__ X, int n,
                           const int* __restrict__ blockHist,
                           const int* __restrict__ regionPS,
                           float4* __restrict__ bucket, float4* __restrict__ zeroC) {
    __shared__ int cur[NREG];
    for (int i = threadIdx.x; i < NREG; i += blockDim.x) cur[i] = 0;
    __syncthreads();
    int stride = gridDim.x * blockDim.x;
    for (int i = blockIdx.x * blockDim.x + threadIdx.x; i < n; i += stride) {
        float x = X[3 * i + 0], y = X[3 * i + 1], z = X[3 * i + 2];
        int r = regOf(binf(x), binf(y), binf(z));
        int pos = regionPS[r] + blockHist[blockIdx.x * NREG + r] + atomicAdd(&cur[r], 1);
        bucket[pos] = make_float4(x, y, z, __int_as_float(i));
    }
    for (int i = blockIdx.x * blockDim.x + threadIdx.x; i < CELLS; i += stride)
        zeroC[i] = make_float4(0.f, 0.f, 0.f, 0.f);
}

// ---- pass B: one block/region — LDS int-atomic accumulate, compact, PIdx ----
__launch_bounds__(BLK)
__global__ void k_binB(const float4* __restrict__ bucket, const int* __restrict__ regionPS,
                       float4* __restrict__ A, int* __restrict__ E0,
                       int* __restrict__ PIdx, int* __restrict__ gM0) {
    __shared__ unsigned long long aX[RC3], aY[RC3], aZ[RC3];
    __shared__ unsigned aC[RC3];
    __shared__ int cidx[RC3];
    __shared__ int cnt, cur, sBase;
    int r = blockIdx.x;
    for (int c = threadIdx.x; c < RC3; c += blockDim.x) {
        aX[c] = 0ull; aY[c] = 0ull; aZ[c] = 0ull; aC[c] = 0u;
    }
    if (threadIdx.x == 0) { cnt = 0; cur = 0; }
    __syncthreads();
    int start = regionPS[r], end = regionPS[r + 1];
    for (int i = start + threadIdx.x; i < end; i += blockDim.x) {
        float4 p = bucket[i];
        int lc = lcOf(binf(p.x), binf(p.y), binf(p.z));
        atomicAdd(&aX[lc], (unsigned long long)(long long)rintf(p.x * FPS));
        atomicAdd(&aY[lc], (unsigned long long)(long long)rintf(p.y * FPS));
        atomicAdd(&aZ[lc], (unsigned long long)(long long)rintf(p.z * FPS));
        atomicAdd(&aC[lc], 1u);
    }
    __syncthreads();
    int myc = 0;
    for (int c = threadIdx.x; c < RC3; c += blockDim.x)
        if (aC[c] > 0u) ++myc;
    if (myc) atomicAdd(&cnt, myc);
    __syncthreads();
    if (threadIdx.x == 0 && cnt > 0) sBase = atomicAdd(gM0, cnt);
    __syncthreads();
    int rx = r / (RDIM * RDIM), ry = (r / RDIM) % RDIM, rz = r % RDIM;
    for (int c = threadIdx.x; c < RC3; c += blockDim.x) {
        if (aC[c] > 0u) {
            int idx = sBase + atomicAdd(&cur, 1);
            cidx[c] = idx;
            int bx = rx * RC + c / (RC * RC);
            int by = ry * RC + (c / RC) % RC;
            int bz = rz * RC + c % RC;
            int b = flatb(bx, by, bz);
            E0[idx] = b;
            A[b] = make_float4((float)((double)(long long)aX[c] * FPSI),
                               (float)((double)(long long)aY[c] * FPSI),
                               (float)((double)(long long)aZ[c] * FPSI),
                               (float)aC[c]);
        }
    }
    __syncthreads();
    for (int i = start + threadIdx.x; i < end; i += blockDim.x) {
        float4 p = bucket[i];
        int lc = lcOf(binf(p.x), binf(p.y), binf(p.z));
        PIdx[__float_as_int(p.w)] = cidx[lc];
    }
}

// ---- fused per-step kernel ----
// Blocks [0, BC): conv, 51 items/chunk, 5 threads/item (one dx-plane each),
//   row-contiguous taps, LDS reduce; finalize by wave 0 with head-flag
//   segmented dedup (adjacent equal targets merge; leaders issue pk_add).
//   NO occupancy-mask atomics: next list is rebuilt from tgt.w by k_compactG.
// Blocks [BC, NF): grid-stride misc (upd / targeted clear).
__launch_bounds__(BLK)
__global__ void k_fused(
    const float4* __restrict__ src, const int* __restrict__ list, const int* __restrict__ pK,
    float4* __restrict__ REo, int* __restrict__ IDXo, float4* __restrict__ eposInit,
    float4* __restrict__ tgt,
    int updS, const float* __restrict__ X, int n, const int* __restrict__ PIdx,
    const float4* __restrict__ REp, const int* __restrict__ IDXp,
    const int* __restrict__ pM0, float4* __restrict__ epos,
    unsigned* __restrict__ notConv,
    const int* __restrict__ clearList, const int* __restrict__ pKc,
    float4* __restrict__ clearGrid, int lastStep) {
    __shared__ float4 sh[BLK];
    __shared__ unsigned sFlag;
    if (threadIdx.x == 0) sFlag = 0;
    __syncthreads();
    int K = *pK;
    int NC = (K + IPB - 1) / IPB;        // total conv chunks
    int BC = NC;
    if (BC > NF - 256) BC = NF - 256;    // always keep misc blocks
    const float t5[5] = {1.f, 2.f, 3.f, 2.f, 1.f};
    bool moved = false;

    if ((int)blockIdx.x < BC) {
        // ---------------- conv blocks ----------------
        int first, last, step;
        if (BC >= 64) {   // XCD-contiguous chunk ranges (measured neutral, kept)
            int xcd = blockIdx.x & 7, loc = blockIdx.x >> 3;
            int cpx = (NC + 7) >> 3;
            int bpx = ((BC - 1 - xcd) >> 3) + 1;
            first = xcd * cpx + loc;
            last = (xcd + 1) * cpx; if (last > NC) last = NC;
            step = bpx;
        } else {
            first = blockIdx.x; last = NC; step = BC;
        }
        for (int ib = first; ib < last; ib += step) {
            int li = threadIdx.x / 5;
            int dx = threadIdx.x % 5;
            int item = ib * IPB + li;
            float4 part = make_float4(0.f, 0.f, 0.f, 0.f);
            if (li < IPB && item < K) {
                int b = list[item];
                int bx = b / DIM2, rem = b % DIM2;
                int by = rem / DIM, bz = rem % DIM;
                int ix = bx + dx - 2;
                if ((unsigned)ix < (unsigned)DIM) {
                    float wx = t5[dx];
                    if (by >= 2 && by <= DIM - 3 && bz >= 2 && bz <= DIM - 3) {
                        #pragma unroll
                        for (int dy = 0; dy < 5; ++dy) {
                            float wxy = wx * t5[dy];
                            const float4* row = src + flatb(ix, by + dy - 2, bz - 2);
                            #pragma unroll
                            for (int dz = 0; dz < 5; ++dz) {
                                float w = wxy * t5[dz];
                                float4 e = row[dz];
                                part.x = fmaf(w, e.x, part.x);
                                part.y = fmaf(w, e.y, part.y);
                                part.z = fmaf(w, e.z, part.z);
                                part.w = fmaf(w, e.w, part.w);
                            }
                        }
                    } else {
                        for (int dy = 0; dy < 5; ++dy) {
                            int iy = by + dy - 2;
                            if ((unsigned)iy >= (unsigned)DIM) continue;
                            float wxy = wx * t5[dy];
                            for (int dz = 0; dz < 5; ++dz) {
                                int iz = bz + dz - 2;
                                if ((unsigned)iz >= (unsigned)DIM) continue;
                                float w = wxy * t5[dz];
                                float4 e = src[flatb(ix, iy, iz)];
                                part.x = fmaf(w, e.x, part.x);
                                part.y = fmaf(w, e.y, part.y);
                                part.z = fmaf(w, e.z, part.z);
                                part.w = fmaf(w, e.w, part.w);
                            }
                        }
                    }
                }
            }
            sh[threadIdx.x] = part;
            __syncthreads();
            if (threadIdx.x < 64) {
                // finalize by wave 0; head-flag segmented dedup on target bin
                int item2 = ib * IPB + threadIdx.x;
                bool valid = (threadIdx.x < IPB) && (item2 < K);
                int bn = -1;
                float4 sv = make_float4(0.f, 0.f, 0.f, 0.f);
                if (valid) {
                    int base5 = threadIdx.x * 5;
                    float4 a0 = sh[base5 + 0], a1 = sh[base5 + 1], a2 = sh[base5 + 2];
                    float4 a3 = sh[base5 + 3], a4 = sh[base5 + 4];
                    float sx = a0.x + a1.x + a2.x + a3.x + a4.x;
                    float sy = a0.y + a1.y + a2.y + a3.y + a4.y;
                    float sz = a0.z + a1.z + a2.z + a3.z + a4.z;
                    float sc = a0.w + a1.w + a2.w + a3.w + a4.w;
                    int b = list[item2];
                    float W = src[b].w;     // center count (occupied => sc>0)
                    float4 np = make_float4(sx / sc, sy / sc, sz / sc, W);
                    REo[item2] = np;
                    IDXo[b] = item2;
                    if (eposInit) eposInit[item2] = np;
                    if (!lastStep) {
                        bn = flatb(binf(np.x), binf(np.y), binf(np.z));
                        sv = make_float4(W * np.x, W * np.y, W * np.z, W);
                    }
                }
                if (!lastStep) {
                    // run heads: first lane or key differs from previous lane
                    int pbn = __shfl_up(bn, 1, 64);
                    unsigned f = (threadIdx.x == 0 || pbn != bn) ? 1u : 0u;
                    // leader = run end (next lane is a head, or last lane)
                    unsigned nf = __shfl_down(f, 1, 64);
                    bool leader = valid && (threadIdx.x == 63 || nf != 0u);
                    // flagged Hillis-Steele segmented inclusive sum
                    #pragma unroll
                    for (int off = 1; off < 64; off <<= 1) {
                        float ox = __shfl_up(sv.x, off, 64);
                        float oy = __shfl_up(sv.y, off, 64);
                        float oz = __shfl_up(sv.z, off, 64);
                        float ow = __shfl_up(sv.w, off, 64);
                        unsigned of = __shfl_up(f, off, 64);
                        if ((int)threadIdx.x >= off) {
                            if (!f) { sv.x += ox; sv.y += oy; sv.z += oz; sv.w += ow; }
                            f |= of;
                        }
                    }
                    if (leader) {
                        float* cell = (float*)&tgt[bn];
                        pk_add(cell + 0, sv.x, sv.y);
                        pk_add(cell + 2, sv.z, sv.w);
                    }
                }
            }
            __syncthreads();    // sh reuse
        }
    } else {
        // ---------------- misc blocks ----------------
        int U = (updS > 0) ? (X ? n : *pM0) : 0;
        int CL = clearList ? *pKc : 0;
        int total = U + CL;
        bool done = false;
        if (updS > 1) {
            for (int t = 1; t < updS; ++t) done |= (notConv[t] == 0u);
        }
        int stride = (NF - BC) * blockDim.x;
        for (int idx = (blockIdx.x - BC) * blockDim.x + threadIdx.x; idx < total;
             idx += stride) {
            if (idx < U) {
                int e = idx;
                if (X) {  // per-point step-1 convergence via PIdx
                    float x = X[3 * e + 0], y = X[3 * e + 1], z = X[3 * e + 2];
                    float4 rr = REp[PIdx[e]];
                    float ex = rr.x - x, ey = rr.y - y, ez = rr.z - z;
                    moved |= (fmaf(ex, ex, fmaf(ey, ey, ez * ez)) > TOL2);
                } else if (!done) {  // per-entry update to step-updS position
                    float4 p = epos[e];
                    int j = IDXp[flatb(binf(p.x), binf(p.y), binf(p.z))];
                    float4 rr = REp[j];
                    float ex = rr.x - p.x, ey = rr.y - p.y, ez = rr.z - p.z;
                    moved |= (fmaf(ex, ex, fmaf(ey, ey, ez * ez)) > TOL2);
                    epos[e] = make_float4(rr.x, rr.y, rr.z, p.w);
                }
            } else {
                clearGrid[clearList[idx - U]] = make_float4(0.f, 0.f, 0.f, 0.f);
            }
        }
    }
    if (moved) sFlag = 1;
    __syncthreads();
    if (threadIdx.x == 0 && updS > 0 && sFlag) notConv[updS] = 1u;
}

// ---- scatter-grid -> bin-sorted list: stream .w channel, compact indices ----
// Thread t owns 32 consecutive cells; block scan over per-thread counts; one
// atomicAdd per block. Output sorted within each block's 8192-cell range.
__launch_bounds__(BLK)
__global__ void k_compactG(const float4* __restrict__ G, int* __restrict__ listOut,
                           int* __restrict__ pKout) {
    __shared__ int scan[BLK];
    __shared__ int sBase;
    const float* __restrict__ Gw = (const float*)G;
    int base = (blockIdx.x * BLK + threadIdx.x) * CPT;
    int c = 0;
    #pragma unroll 4
    for (int k = 0; k < CPT; ++k) {
        int i = base + k;
        if (i < CELLS && Gw[4 * i + 3] > 0.f) ++c;
    }
    scan[threadIdx.x] = c;
    __syncthreads();
    for (int d = 1; d < BLK; d <<= 1) {
        int add = (threadIdx.x >= (unsigned)d) ? scan[threadIdx.x - d] : 0;
        __syncthreads();
        scan[threadIdx.x] += add;
        __syncthreads();
    }
    if (threadIdx.x == BLK - 1) {
        int tot = scan[BLK - 1];
        sBase = tot ? atomicAdd(pKout, tot) : 0;
    }
    __syncthreads();
    int pos = sBase + scan[threadIdx.x] - c;
    for (int k = 0; k < CPT; ++k) {
        int i = base + k;
        if (i < CELLS && Gw[4 * i + 3] > 0.f) listOut[pos++] = i;
    }
}

// ---- per-point output: gather epos via PIdx, optional last hop via REa/IDXa ----
__global__ void k_map(const int* __restrict__ PIdx, int n, const float4* __restrict__ epos,
                      const float4* __restrict__ REa, const int* __restrict__ IDXa,
                      const unsigned* __restrict__ notConv, float* __restrict__ out) {
    bool done = false;
    for (int t = 1; t <= 4; ++t) done |= (notConv[t] == 0u);
    int i = blockIdx.x * blockDim.x + threadIdx.x;
    if (i >= n) return;
    float4 p = epos[PIdx[i]];
    if (!done) {
        float4 rr = REa[IDXa[flatb(binf(p.x), binf(p.y), binf(p.z))]];
        p.x = rr.x; p.y = rr.y; p.z = rr.z;
    }
    out[3 * i + 0] = p.x;
    out[3 * i + 1] = p.y;
    out[3 * i + 2] = p.z;
}

extern "C" void kernel_launch(void* const* d_in, const int* in_sizes, int n_in,
                              void* d_out, int out_size, void* d_ws, size_t ws_size,
                              hipStream_t stream) {
    const float* X = (const float*)d_in[0];
    int n = in_sizes[0] / 3;

    char* ws = (char*)d_ws;
    int*      cnt     = (int*)ws;        // cnt[1..5] list sizes
    unsigned* notConv = (unsigned*)(ws + 32);
    size_t gB = (size_t)CELLS * 16;
    float4* A = (float4*)(ws + 256);
    float4* B = (float4*)((char*)A + gB);
    float4* C = (float4*)((char*)B + gB);
    int* IDXa = (int*)((char*)C + gB);
    int* IDXb = IDXa + CELLS;
    float4* REa  = (float4*)(IDXb + CELLS);
    float4* REb  = REa + n;
    float4* epos = REb + n;
    int* E0   = (int*)(epos + n);
    int* La   = E0 + n;
    int* Lb   = La + n;
    int* Lc   = Lb + n;
    int* Ld   = Lc + n;
    int* PIdx = Ld + n;
    float4* bucket = (float4*)(PIdx + n);
    int* blockHist = (int*)(bucket + n);
    int* regionPS  = blockHist + NB_A * NREG;

    // meta only (A,B zeroed in histA, C in scatterA; no masks anymore)
    hipMemsetAsync(ws, 0, 256, stream);

    k_histA<<<NB_A, BLK, 0, stream>>>(X, n, blockHist, A, B);
    k_colscan<<<NREG / BLK, BLK, 0, stream>>>(blockHist, regionPS);
    k_regprefix<<<1, 1024, 0, stream>>>(regionPS);
    k_scatterA<<<NB_A, BLK, 0, stream>>>(X, n, blockHist, regionPS, bucket, C);
    k_binB<<<NREG, BLK, 0, stream>>>(bucket, regionPS, A, E0, PIdx, &cnt[1]);

    // F1: conv A/E0 -> REa/IDXa (+epos init); scatter->B
    k_fused<<<NF, BLK, 0, stream>>>(A, E0, &cnt[1], REa, IDXa, epos,
                                    B,
                                    0, nullptr, n, nullptr, nullptr, nullptr, nullptr,
                                    nullptr, notConv, nullptr, nullptr, nullptr, 0);
    k_compactG<<<NBG, BLK, 0, stream>>>(B, La, &cnt[2]);
    // F2: conv B/La -> REb/IDXb; scatter->C; upd1 via PIdx (REa); clear A via E0
    k_fused<<<NF, BLK, 0, stream>>>(B, La, &cnt[2], REb, IDXb, nullptr,
                                    C,
                                    1, X, n, PIdx, REa, IDXa, &cnt[1], nullptr,
                                    notConv, E0, &cnt[1], A, 0);
    k_compactG<<<NBG, BLK, 0, stream>>>(C, Lb, &cnt[3]);
    // F3: conv C/Lb -> REa/IDXa; scatter->A; upd2 (REb/IDXb); clear B via La
    k_fused<<<NF, BLK, 0, stream>>>(C, Lb, &cnt[3], REa, IDXa, nullptr,
                                    A,
                                    2, nullptr, n, nullptr, REb, IDXb, &cnt[1], epos,
                                    notConv, La, &cnt[2], B, 0);
    k_compactG<<<NBG, BLK, 0, stream>>>(A, Lc, &cnt[4]);
    // F4: conv A/Lc -> REb/IDXb; scatter->B; upd3 (REa/IDXa)
    k_fused<<<NF, BLK, 0, stream>>>(A, Lc, &cnt[4], REb, IDXb, nullptr,
                                    B,
                                    3, nullptr, n, nullptr, REa, IDXa, &cnt[1], epos,
                                    notConv, nullptr, nullptr, nullptr, 0);
    k_compactG<<<NBG, BLK, 0, stream>>>(B, Ld, &cnt[5]);
    // F5: conv B/Ld -> REa/IDXa (conv only); upd4 (REb/IDXb)
    k_fused<<<NF, BLK, 0, stream>>>(B, Ld, &cnt[5], REa, IDXa, nullptr,
                                    nullptr,
                                    4, nullptr, n, nullptr, REb, IDXb, &cnt[1], epos,
                                    notConv, nullptr, nullptr, nullptr, 1);

    k_map<<<(n + BLK - 1) / BLK, BLK, 0, stream>>>(PIdx, n, epos, REa, IDXa,
                                                   notConv, (float*)d_out);
}

// Round 6
// 245.584 us; speedup vs baseline: 1.2226x; 1.1446x over previous
//
#include <hip/hip_runtime.h>

// MeanShift++ dense-grid, distinct-bin formulation, v18 = EXACT v12 (246us,
// best measured) + two strictly-additive levers:
// 1) CONVERGED EARLY-EXIT: conv blocks of F3/F4/F5 check notConv flags
//    written by EARLIER dispatches (F3: t=1; F4: t=1,2; F5: t=1,2,3) and
//    skip the entire conv phase when the pipeline is frozen -- outputs are
//    provably unread then (k_fin/upd take the epos path). Zero cost if the
//    data never converges early.
// 2) CENTER-W STASH: finalize's serial chain had a dependent scattered
//    src[b].w load; the dx==2 gather thread stashes it to LDS during the
//    parallel gather phase (same line as its taps), finalize reads LDS.
// Bottleneck model (v13-v17 joint evidence): conv is bound by unique-line
// traffic (~14MB fetch + 11MB atomic write per step at 450-700 GB/s,
// latency/coherence-limited scattered lines), NOT taps (v14: 25-tap conv
// identical), NOT finalize width (v15), NOT balance (v16), NOT atomicOr
// (v17), NOT list order beyond sortedness (v13).
// Dead levers (measured): grid-derived lists (v17, +35us: strided .w scan),
// chunk work-steal queue (v16, +54us), 4-wave finalize + mask pre-test
// (v15, +14us), separable z-pass (v14, +36us), unsorted append list (v13,
// +44us), region-LDS-tile conv (r11, -52%), flattened-tap (r8, -78%).

constexpr float BW   = 0.1f;
constexpr float TOL2 = 1e-6f;            // (1e-3)^2
constexpr int DIM  = 112, OFF = 56;      // bins in [-56,55]; |x|<5.6 covered
constexpr int DIM2 = DIM * DIM;
constexpr int CELLS = DIM * DIM * DIM;   // 1,404,928
constexpr int CLW = CELLS / 32;          // 43,904 mask words
constexpr int RDIM = 16, RC = 7;         // 16^3 regions of 7^3 cells
constexpr int NREG = RDIM * RDIM * RDIM; // 4096
constexpr int RC3 = RC * RC * RC;        // 343
constexpr int NB_A = 128, BLK = 256;
constexpr int NF = 2048;                 // k_fused grid
constexpr int IPB = 51;                  // conv items per block (51*5=255 thr)
constexpr float FPS = 16777216.0f;       // 2^24 fixed-point scale
constexpr double FPSI = 1.0 / 16777216.0;

typedef float vf2 __attribute__((ext_vector_type(2)));

__device__ __forceinline__ int clampb(int v) { return v < 0 ? 0 : (v > DIM - 1 ? DIM - 1 : v); }
__device__ __forceinline__ int binf(float v) { return clampb((int)(v / BW) + OFF); }  // IEEE div+trunc == ref
__device__ __forceinline__ int flatb(int bx, int by, int bz) { return (bx * DIM + by) * DIM + bz; }
__device__ __forceinline__ int regOf(int bx, int by, int bz) {
    return ((bx / RC) * RDIM + (by / RC)) * RDIM + (bz / RC);
}
__device__ __forceinline__ int lcOf(int bx, int by, int bz) {
    return ((bx % RC) * RC + (by % RC)) * RC + (bz % RC);
}

__device__ __forceinline__ void pk_add(float* p, float a, float b) {
#if defined(__has_builtin) && __has_builtin(__builtin_amdgcn_global_atomic_fadd_v2f32)
    vf2 v = {a, b};
    __builtin_amdgcn_global_atomic_fadd_v2f32((vf2*)p, v);
#else
    atomicAdd(p, a);
    atomicAdd(p + 1, b);
#endif
}

// ---- pass A1: per-block region histogram (LDS) + streaming zero of grids A,B ----
__launch_bounds__(BLK)
__global__ void k_histA(const float* __restrict__ X, int n, int* __restrict__ blockHist,
                        float4* __restrict__ zeroA, float4* __restrict__ zeroB) {
    __shared__ int h[NREG];
    for (int i = threadIdx.x; i < NREG; i += blockDim.x) h[i] = 0;
    __syncthreads();
    int stride = gridDim.x * blockDim.x;
    for (int i = blockIdx.x * blockDim.x + threadIdx.x; i < n; i += stride) {
        float x = X[3 * i + 0], y = X[3 * i + 1], z = X[3 * i + 2];
        atomicAdd(&h[regOf(binf(x), binf(y), binf(z))], 1);
    }
    __syncthreads();
    for (int i = threadIdx.x; i < NREG; i += blockDim.x)
        blockHist[blockIdx.x * NREG + i] = h[i];
    for (int i = blockIdx.x * blockDim.x + threadIdx.x; i < CELLS; i += stride) {
        zeroA[i] = make_float4(0.f, 0.f, 0.f, 0.f);
        zeroB[i] = make_float4(0.f, 0.f, 0.f, 0.f);
    }
}

// ---- pass A2: per-region column scan over blocks ----
__global__ void k_colscan(int* __restrict__ blockHist, int* __restrict__ regionPS) {
    int r = blockIdx.x * blockDim.x + threadIdx.x;
    if (r >= NREG) return;
    int run = 0;
    for (int b = 0; b < NB_A; ++b) {
        int idx = b * NREG + r;
        int v = blockHist[idx];
        blockHist[idx] = run;
        run += v;
    }
    regionPS[r] = run;
}

// ---- pass A3: exclusive prefix over 4096 region totals ----
__launch_bounds__(1024)
__global__ void k_regprefix(int* __restrict__ regionPS) {
    __shared__ int buf[1024];
    int t = threadIdx.x;
    int v0 = regionPS[4 * t + 0], v1 = regionPS[4 * t + 1];
    int v2 = regionPS[4 * t + 2], v3 = regionPS[4 * t + 3];
    int s = v0 + v1 + v2 + v3;
    buf[t] = s;
    __syncthreads();
    for (int d = 1; d < 1024; d <<= 1) {
        int add = (t >= d) ? buf[t - d] : 0;
        __syncthreads();
        buf[t] += add;
        __syncthreads();
    }
    int excl = buf[t] - s;
    regionPS[4 * t + 0] = excl;
    regionPS[4 * t + 1] = excl + v0;
    regionPS[4 * t + 2] = excl + v0 + v1;
    regionPS[4 * t + 3] = excl + v0 + v1 + v2;
    if (t == 1023) regionPS[4096] = buf[1023];
}

// ---- pass A4: scatter points into region buckets + streaming zero of grid C ----
__launch_bounds__(BLK)
__global__ void k_scatterA(const float* __restrict__ X, int n,
                           const int* __restrict__ blockHist,
                           const int* __restrict__ regionPS,
                           float4* __restrict__ bucket, float4* __restrict__ zeroC) {
    __shared__ int cur[NREG];
    for (int i = threadIdx.x; i < NREG; i += blockDim.x) cur[i] = 0;
    __syncthreads();
    int stride = gridDim.x * blockDim.x;
    for (int i = blockIdx.x * blockDim.x + threadIdx.x; i < n; i += stride) {
        float x = X[3 * i + 0], y = X[3 * i + 1], z = X[3 * i + 2];
        int r = regOf(binf(x), binf(y), binf(z));
        int pos = regionPS[r] + blockHist[blockIdx.x * NREG + r] + atomicAdd(&cur[r], 1);
        bucket[pos] = make_float4(x, y, z, __int_as_float(i));
    }
    for (int i = blockIdx.x * blockDim.x + threadIdx.x; i < CELLS; i += stride)
        zeroC[i] = make_float4(0.f, 0.f, 0.f, 0.f);
}

// ---- pass B: one block/region — LDS int-atomic accumulate, compact, PIdx ----
__launch_bounds__(BLK)
__global__ void k_binB(const float4* __restrict__ bucket, const int* __restrict__ regionPS,
                       float4* __restrict__ A, int* __restrict__ E0,
                       int* __restrict__ PIdx, int* __restrict__ gM0) {
    __shared__ unsigned long long aX[RC3], aY[RC3], aZ[RC3];
    __shared__ unsigned aC[RC3];
    __shared__ int cidx[RC3];
    __shared__ int cnt, cur, sBase;
    int r = blockIdx.x;
    for (int c = threadIdx.x; c < RC3; c += blockDim.x) {
        aX[c] = 0ull; aY[c] = 0ull; aZ[c] = 0ull; aC[c] = 0u;
    }
    if (threadIdx.x == 0) { cnt = 0; cur = 0; }
    __syncthreads();
    int start = regionPS[r], end = regionPS[r + 1];
    for (int i = start + threadIdx.x; i < end; i += blockDim.x) {
        float4 p = bucket[i];
        int lc = lcOf(binf(p.x), binf(p.y), binf(p.z));
        atomicAdd(&aX[lc], (unsigned long long)(long long)rintf(p.x * FPS));
        atomicAdd(&aY[lc], (unsigned long long)(long long)rintf(p.y * FPS));
        atomicAdd(&aZ[lc], (unsigned long long)(long long)rintf(p.z * FPS));
        atomicAdd(&aC[lc], 1u);
    }
    __syncthreads();
    int myc = 0;
    for (int c = threadIdx.x; c < RC3; c += blockDim.x)
        if (aC[c] > 0u) ++myc;
    if (myc) atomicAdd(&cnt, myc);
    __syncthreads();
    if (threadIdx.x == 0 && cnt > 0) sBase = atomicAdd(gM0, cnt);
    __syncthreads();
    int rx = r / (RDIM * RDIM), ry = (r / RDIM) % RDIM, rz = r % RDIM;
    for (int c = threadIdx.x; c < RC3; c += blockDim.x) {
        if (aC[c] > 0u) {
            int idx = sBase + atomicAdd(&cur, 1);
            cidx[c] = idx;
            int bx = rx * RC + c / (RC * RC);
            int by = ry * RC + (c / RC) % RC;
            int bz = rz * RC + c % RC;
            int b = flatb(bx, by, bz);
            E0[idx] = b;
            A[b] = make_float4((float)((double)(long long)aX[c] * FPSI),
                               (float)((double)(long long)aY[c] * FPSI),
                               (float)((double)(long long)aZ[c] * FPSI),
                               (float)aC[c]);
        }
    }
    __syncthreads();
    for (int i = start + threadIdx.x; i < end; i += blockDim.x) {
        float4 p = bucket[i];
        int lc = lcOf(binf(p.x), binf(p.y), binf(p.z));
        PIdx[__float_as_int(p.w)] = cidx[lc];
    }
}

// ---- fused per-step kernel ----
// Blocks [0, BC): conv, 51 items/chunk, 5 threads/item (one dx-plane each),
//   row-contiguous taps, LDS reduce; finalize by wave 0 with head-flag
//   segmented dedup (adjacent equal targets merge; leaders issue atomics).
//   chkMask: bitmask of notConv[t] (written by EARLIER dispatches) -- if any
//   checked flag is 0 the pipeline is frozen and conv is skipped entirely.
// Blocks [BC, NF): grid-stride misc (upd / targeted clear).
__launch_bounds__(BLK)
__global__ void k_fused(
    const float4* __restrict__ src, const int* __restrict__ list, const int* __restrict__ pK,
    float4* __restrict__ REo, int* __restrict__ IDXo, float4* __restrict__ eposInit,
    float4* __restrict__ tgt, unsigned* __restrict__ clT,
    int updS, const float* __restrict__ X, int n, const int* __restrict__ PIdx,
    const float4* __restrict__ REp, const int* __restrict__ IDXp,
    const int* __restrict__ pM0, float4* __restrict__ epos,
    unsigned* __restrict__ notConv,
    const int* __restrict__ clearList, const int* __restrict__ pKc,
    float4* __restrict__ clearGrid, int chkMask, int lastStep) {
    __shared__ float4 sh[BLK];
    __shared__ float shW[IPB];
    __shared__ unsigned sFlag;
    if (threadIdx.x == 0) sFlag = 0;
    __syncthreads();
    int K = *pK;
    int NC = (K + IPB - 1) / IPB;        // total conv chunks
    int BC = NC;
    if (BC > NF - 256) BC = NF - 256;    // always keep misc blocks
    const float t5[5] = {1.f, 2.f, 3.f, 2.f, 1.f};
    bool moved = false;

    if ((int)blockIdx.x < BC) {
        // ---------------- conv blocks ----------------
        bool frozen = false;
        if (chkMask) {
            #pragma unroll
            for (int t = 1; t <= 4; ++t)
                if ((chkMask >> t) & 1) frozen |= (notConv[t] == 0u);
        }
        if (!frozen) {
        int first, last, step;
        if (BC >= 64) {   // XCD-contiguous chunk ranges (measured neutral, kept)
            int xcd = blockIdx.x & 7, loc = blockIdx.x >> 3;
            int cpx = (NC + 7) >> 3;
            int bpx = ((BC - 1 - xcd) >> 3) + 1;
            first = xcd * cpx + loc;
            last = (xcd + 1) * cpx; if (last > NC) last = NC;
            step = bpx;
        } else {
            first = blockIdx.x; last = NC; step = BC;
        }
        for (int ib = first; ib < last; ib += step) {
            int li = threadIdx.x / 5;
            int dx = threadIdx.x % 5;
            int item = ib * IPB + li;
            float4 part = make_float4(0.f, 0.f, 0.f, 0.f);
            if (li < IPB && item < K) {
                int b = list[item];
                int bx = b / DIM2, rem = b % DIM2;
                int by = rem / DIM, bz = rem % DIM;
                if (dx == 2) shW[li] = src[b].w;   // center count -> LDS (parallel phase)
                int ix = bx + dx - 2;
                if ((unsigned)ix < (unsigned)DIM) {
                    float wx = t5[dx];
                    if (by >= 2 && by <= DIM - 3 && bz >= 2 && bz <= DIM - 3) {
                        #pragma unroll
                        for (int dy = 0; dy < 5; ++dy) {
                            float wxy = wx * t5[dy];
                            const float4* row = src + flatb(ix, by + dy - 2, bz - 2);
                            #pragma unroll
                            for (int dz = 0; dz < 5; ++dz) {
                                float w = wxy * t5[dz];
                                float4 e = row[dz];
                                part.x = fmaf(w, e.x, part.x);
                                part.y = fmaf(w, e.y, part.y);
                                part.z = fmaf(w, e.z, part.z);
                                part.w = fmaf(w, e.w, part.w);
                            }
                        }
                    } else {
                        for (int dy = 0; dy < 5; ++dy) {
                            int iy = by + dy - 2;
                            if ((unsigned)iy >= (unsigned)DIM) continue;
                            float wxy = wx * t5[dy];
                            for (int dz = 0; dz < 5; ++dz) {
                                int iz = bz + dz - 2;
                                if ((unsigned)iz >= (unsigned)DIM) continue;
                                float w = wxy * t5[dz];
                                float4 e = src[flatb(ix, iy, iz)];
                                part.x = fmaf(w, e.x, part.x);
                                part.y = fmaf(w, e.y, part.y);
                                part.z = fmaf(w, e.z, part.z);
                                part.w = fmaf(w, e.w, part.w);
                            }
                        }
                    }
                }
            }
            sh[threadIdx.x] = part;
            __syncthreads();
            if (threadIdx.x < 64) {
                // finalize by wave 0; head-flag segmented dedup on target bin
                int item2 = ib * IPB + threadIdx.x;
                bool valid = (threadIdx.x < IPB) && (item2 < K);
                int bn = -1;
                float4 sv = make_float4(0.f, 0.f, 0.f, 0.f);
                if (valid) {
                    int base5 = threadIdx.x * 5;
                    float4 a0 = sh[base5 + 0], a1 = sh[base5 + 1], a2 = sh[base5 + 2];
                    float4 a3 = sh[base5 + 3], a4 = sh[base5 + 4];
                    float sx = a0.x + a1.x + a2.x + a3.x + a4.x;
                    float sy = a0.y + a1.y + a2.y + a3.y + a4.y;
                    float sz = a0.z + a1.z + a2.z + a3.z + a4.z;
                    float sc = a0.w + a1.w + a2.w + a3.w + a4.w;
                    int b = list[item2];
                    float W = shW[threadIdx.x];   // center count via LDS stash
                    float4 np = make_float4(sx / sc, sy / sc, sz / sc, W);
                    REo[item2] = np;
                    IDXo[b] = item2;
                    if (eposInit) eposInit[item2] = np;
                    if (!lastStep) {
                        bn = flatb(binf(np.x), binf(np.y), binf(np.z));
                        sv = make_float4(W * np.x, W * np.y, W * np.z, W);
                    }
                }
                if (!lastStep) {
                    // run heads: first lane or key differs from previous lane
                    int pbn = __shfl_up(bn, 1, 64);
                    unsigned f = (threadIdx.x == 0 || pbn != bn) ? 1u : 0u;
                    // leader = run end (next lane is a head, or last lane)
                    unsigned nf = __shfl_down(f, 1, 64);
                    bool leader = valid && (threadIdx.x == 63 || nf != 0u);
                    // flagged Hillis-Steele segmented inclusive sum
                    #pragma unroll
                    for (int off = 1; off < 64; off <<= 1) {
                        float ox = __shfl_up(sv.x, off, 64);
                        float oy = __shfl_up(sv.y, off, 64);
                        float oz = __shfl_up(sv.z, off, 64);
                        float ow = __shfl_up(sv.w, off, 64);
                        unsigned of = __shfl_up(f, off, 64);
                        if ((int)threadIdx.x >= off) {
                            if (!f) { sv.x += ox; sv.y += oy; sv.z += oz; sv.w += ow; }
                            f |= of;
                        }
                    }
                    if (leader) {
                        float* cell = (float*)&tgt[bn];
                        pk_add(cell + 0, sv.x, sv.y);
                        pk_add(cell + 2, sv.z, sv.w);
                        atomicOr(&clT[(unsigned)bn >> 5], 1u << (bn & 31));
                    }
                }
            }
            __syncthreads();    // sh reuse
        }
        }
    } else {
        // ---------------- misc blocks ----------------
        int U = (updS > 0) ? (X ? n : *pM0) : 0;
        int CL = clearList ? *pKc : 0;
        int total = U + CL;
        bool done = false;
        if (updS > 1) {
            for (int t = 1; t < updS; ++t) done |= (notConv[t] == 0u);
        }
        int stride = (NF - BC) * blockDim.x;
        for (int idx = (blockIdx.x - BC) * blockDim.x + threadIdx.x; idx < total;
             idx += stride) {
            if (idx < U) {
                int e = idx;
                if (X) {  // per-point step-1 convergence via PIdx
                    float x = X[3 * e + 0], y = X[3 * e + 1], z = X[3 * e + 2];
                    float4 rr = REp[PIdx[e]];
                    float ex = rr.x - x, ey = rr.y - y, ez = rr.z - z;
                    moved |= (fmaf(ex, ex, fmaf(ey, ey, ez * ez)) > TOL2);
                } else if (!done) {  // per-entry update to step-updS position
                    float4 p = epos[e];
                    int j = IDXp[flatb(binf(p.x), binf(p.y), binf(p.z))];
                    float4 rr = REp[j];
                    float ex = rr.x - p.x, ey = rr.y - p.y, ez = rr.z - p.z;
                    moved |= (fmaf(ex, ex, fmaf(ey, ey, ez * ez)) > TOL2);
                    epos[e] = make_float4(rr.x, rr.y, rr.z, p.w);
                }
            } else {
                clearGrid[clearList[idx - U]] = make_float4(0.f, 0.f, 0.f, 0.f);
            }
        }
    }
    if (moved) sFlag = 1;
    __syncthreads();
    if (threadIdx.x == 0 && updS > 0 && sFlag) notConv[updS] = 1u;
}

// ---- mask -> bin-sorted list (block scan, 1 atomic/block), clears mask ----
__launch_bounds__(BLK)
__global__ void k_compactM(unsigned* __restrict__ mask, int* __restrict__ listOut,
                           int* __restrict__ pKout) {
    __shared__ int scan[BLK];
    __shared__ int sBase;
    int i = blockIdx.x * blockDim.x + threadIdx.x;
    unsigned w = (i < CLW) ? mask[i] : 0u;
    if (i < CLW && w) mask[i] = 0u;
    int c = __popc(w);
    scan[threadIdx.x] = c;
    __syncthreads();
    for (int d = 1; d < BLK; d <<= 1) {
        int add = (threadIdx.x >= (unsigned)d) ? scan[threadIdx.x - d] : 0;
        __syncthreads();
        scan[threadIdx.x] += add;
        __syncthreads();
    }
    if (threadIdx.x == BLK - 1) {
        int tot = scan[BLK - 1];
        sBase = tot ? atomicAdd(pKout, tot) : 0;
    }
    __syncthreads();
    int base = sBase + scan[threadIdx.x] - c;
    int bb = i * 32;
    while (w) {
        int b = __ffs(w) - 1;
        listOut[base++] = bb + b;
        w &= w - 1;
    }
}

// ---- finalize: per-entry final position table fpos[e] ----
__launch_bounds__(BLK)
__global__ void k_fin(const float4* __restrict__ REa, const int* __restrict__ IDXa,
                      const float4* __restrict__ epos, const int* __restrict__ pM0,
                      const unsigned* __restrict__ notConv, float4* __restrict__ fpos) {
    int M0 = *pM0;
    bool done = false;
    for (int t = 1; t <= 4; ++t) done |= (notConv[t] == 0u);
    for (int e = blockIdx.x * blockDim.x + threadIdx.x; e < M0;
         e += gridDim.x * blockDim.x) {
        float4 p = epos[e];
        if (!done) {
            float4 rr = REa[IDXa[flatb(binf(p.x), binf(p.y), binf(p.z))]];
            p.x = rr.x; p.y = rr.y; p.z = rr.z;
        }
        fpos[e] = p;
    }
}

// ---- per-point output: single gather through fpos via PIdx ----
__global__ void k_map(const int* __restrict__ PIdx, int n, const float4* __restrict__ fpos,
                      float* __restrict__ out) {
    int i = blockIdx.x * blockDim.x + threadIdx.x;
    if (i >= n) return;
    float4 p = fpos[PIdx[i]];
    out[3 * i + 0] = p.x;
    out[3 * i + 1] = p.y;
    out[3 * i + 2] = p.z;
}

extern "C" void kernel_launch(void* const* d_in, const int* in_sizes, int n_in,
                              void* d_out, int out_size, void* d_ws, size_t ws_size,
                              hipStream_t stream) {
    const float* X = (const float*)d_in[0];
    int n = in_sizes[0] / 3;

    char* ws = (char*)d_ws;
    int*      cnt     = (int*)ws;        // cnt[1..5] list sizes
    unsigned* notConv = (unsigned*)(ws + 32);
    size_t mB = (size_t)CLW * 4;
    size_t gB = (size_t)CELLS * 16;
    unsigned* m0 = (unsigned*)(ws + 256);
    unsigned* m1 = (unsigned*)(ws + 256 + mB);
    float4* A = (float4*)(ws + 256 + 2 * mB);
    float4* B = (float4*)((char*)A + gB);
    float4* C = (float4*)((char*)B + gB);
    int* IDXa = (int*)((char*)C + gB);
    int* IDXb = IDXa + CELLS;
    float4* REa  = (float4*)(IDXb + CELLS);
    float4* REb  = REa + n;
    float4* epos = REb + n;
    int* E0   = (int*)(epos + n);
    int* La   = E0 + n;
    int* Lb   = La + n;
    int* Lc   = Lb + n;
    int* Ld   = Lc + n;
    int* PIdx = Ld + n;
    float4* bucket = (float4*)(PIdx + n);
    int* blockHist = (int*)(bucket + n);
    int* regionPS  = blockHist + NB_A * NREG;

    // meta + masks only (A,B zeroed in histA, C in scatterA)
    hipMemsetAsync(ws, 0, 256 + 2 * mB, stream);

    const int NCM = (CLW + BLK - 1) / BLK;   // compactM blocks

    k_histA<<<NB_A, BLK, 0, stream>>>(X, n, blockHist, A, B);
    k_colscan<<<NREG / BLK, BLK, 0, stream>>>(blockHist, regionPS);
    k_regprefix<<<1, 1024, 0, stream>>>(regionPS);
    k_scatterA<<<NB_A, BLK, 0, stream>>>(X, n, blockHist, regionPS, bucket, C);
    k_binB<<<NREG, BLK, 0, stream>>>(bucket, regionPS, A, E0, PIdx, &cnt[1]);

    // F1: conv A/E0 -> REa/IDXa (+epos init); scatter->B claim m0
    k_fused<<<NF, BLK, 0, stream>>>(A, E0, &cnt[1], REa, IDXa, epos,
                                    B, m0,
                                    0, nullptr, n, nullptr, nullptr, nullptr, nullptr,
                                    nullptr, notConv, nullptr, nullptr, nullptr, 0, 0);
    k_compactM<<<NCM, BLK, 0, stream>>>(m0, La, &cnt[2]);
    // F2: conv B/La -> REb/IDXb; scatter->C claim m1; upd1 via PIdx (REa); clear A via E0
    k_fused<<<NF, BLK, 0, stream>>>(B, La, &cnt[2], REb, IDXb, nullptr,
                                    C, m1,
                                    1, X, n, PIdx, REa, IDXa, &cnt[1], nullptr,
                                    notConv, E0, &cnt[1], A, 0, 0);
    k_compactM<<<NCM, BLK, 0, stream>>>(m1, Lb, &cnt[3]);
    // F3: conv C/Lb -> REa/IDXa; scatter->A claim m0; upd2 (REb/IDXb); clear B via La
    //     conv skipped if notConv[1]==0 (written in F2)
    k_fused<<<NF, BLK, 0, stream>>>(C, Lb, &cnt[3], REa, IDXa, nullptr,
                                    A, m0,
                                    2, nullptr, n, nullptr, REb, IDXb, &cnt[1], epos,
                                    notConv, La, &cnt[2], B, 0b00010, 0);
    k_compactM<<<NCM, BLK, 0, stream>>>(m0, Lc, &cnt[4]);
    // F4: conv A/Lc -> REb/IDXb; scatter->B claim m1; upd3 (REa/IDXa)
    //     conv skipped if notConv[1..2] any 0 (written in F2/F3)
    k_fused<<<NF, BLK, 0, stream>>>(A, Lc, &cnt[4], REb, IDXb, nullptr,
                                    B, m1,
                                    3, nullptr, n, nullptr, REa, IDXa, &cnt[1], epos,
                                    notConv, nullptr, nullptr, nullptr, 0b00110, 0);
    k_compactM<<<NCM, BLK, 0, stream>>>(m1, Ld, &cnt[5]);
    // F5: conv B/Ld -> REa/IDXa (conv only); upd4 (REb/IDXb)
    //     conv skipped if notConv[1..3] any 0 (written in F2/F3/F4)
    k_fused<<<NF, BLK, 0, stream>>>(B, Ld, &cnt[5], REa, IDXa, nullptr,
                                    nullptr, nullptr,
                                    4, nullptr, n, nullptr, REb, IDXb, &cnt[1], epos,
                                    notConv, nullptr, nullptr, nullptr, 0b01110, 1);

    k_fin<<<256, BLK, 0, stream>>>(REa, IDXa, epos, &cnt[1], notConv, REb);
    k_map<<<(n + BLK - 1) / BLK, BLK, 0, stream>>>(PIdx, n, REb, (float*)d_out);
}